// Round 14
// baseline (226.444 us; speedup 1.0000x reference)
//
#include <hip/hip_runtime.h>
#include <math.h>

#define N_NODES 50000
#define F_DIM 64
#define E_EDGES 800000
#define U_DIM 128
#define K_DIM 192
#define EPS_LN 0.001f
#define NB 196           // ceil(N/256) node buckets
#define BN_NODES 256     // nodes per bucket

typedef __attribute__((ext_vector_type(8))) short bf16x8;
typedef __attribute__((ext_vector_type(4))) float f32x4;
typedef __attribute__((ext_vector_type(8))) unsigned short us8;

__device__ __forceinline__ unsigned short f2bf(float x) {
    unsigned u = __builtin_bit_cast(unsigned, x);
    unsigned r = (u + 0x7FFFu + ((u >> 16) & 1u)) >> 16;   // RNE
    return (unsigned short)r;
}
__device__ __forceinline__ float bf2f(unsigned short h) {
    unsigned u = ((unsigned)h) << 16;
    return __builtin_bit_cast(float, u);
}

// ---------------- dtype probe ----------------
__global__ void probe_kernel(const int* __restrict__ e, int* __restrict__ flag) {
    __shared__ int nz;
    if (threadIdx.x == 0) nz = 0;
    __syncthreads();
    int i = threadIdx.x;
    if (e[4 * i + 1] != 0 || e[4 * i + 3] != 0) atomicAdd(&nz, 1);
    __syncthreads();
    if (threadIdx.x == 0) flag[0] = (nz == 0) ? 1 : 0;   // 1 = int64 layout
}

// ---------------- CSR build: 2-level bucket sort, LDS-atomic based ----------------

__global__ void bucket_hist_kernel(const int* __restrict__ edges, const int* __restrict__ flag,
                                   int* __restrict__ bhist, int E) {
    __shared__ int h[NB];
    int tid = threadIdx.x;
    for (int i = tid; i < NB; i += 1024) h[i] = 0;
    __syncthreads();
    int is64 = flag[0];
    int e0 = blockIdx.x * 4096 + tid * 4;
    #pragma unroll
    for (int j = 0; j < 4; ++j) {
        int e = e0 + j;
        if (e < E) {
            int r = is64 ? edges[4 * e] : edges[2 * e];
            atomicAdd(&h[r >> 8], 1);
        }
    }
    __syncthreads();
    for (int i = tid; i < NB; i += 1024) if (h[i]) atomicAdd(&bhist[i], h[i]);
}

__global__ void bucket_scan_kernel(const int* __restrict__ bhist, int* __restrict__ bucketStart,
                                   int* __restrict__ bucketCursor, int E) {
    __shared__ int wtot[4];
    int tid = threadIdx.x;             // 256
    int w = tid >> 6, l = tid & 63;
    int v = (tid < NB) ? bhist[tid] : 0;
    int x = v;
    #pragma unroll
    for (int off = 1; off < 64; off <<= 1) {
        int y = __shfl_up(x, off, 64);
        if (l >= off) x += y;
    }
    if (l == 63) wtot[w] = x;
    __syncthreads();
    int add = 0;
    for (int k = 0; k < w; ++k) add += wtot[k];
    int excl = x - v + add;
    if (tid < NB) { bucketStart[tid] = excl; bucketCursor[tid] = excl; }
    if (tid == 0) bucketStart[NB] = E;
}

__global__ void bucket_scatter_kernel(const int* __restrict__ edges, const int* __restrict__ flag,
                                      int* __restrict__ bucketCursor, unsigned int* __restrict__ tmp, int E) {
    __shared__ int h[NB];
    __shared__ int base[NB];
    int tid = threadIdx.x;
    for (int i = tid; i < NB; i += 1024) h[i] = 0;
    __syncthreads();
    int is64 = flag[0];
    int e0 = blockIdx.x * 4096 + tid * 4;
    int rr[4], ss[4], rk[4];
    #pragma unroll
    for (int j = 0; j < 4; ++j) {
        int e = e0 + j;
        rr[j] = -1; ss[j] = 0; rk[j] = 0;
        if (e < E) {
            if (is64) { rr[j] = edges[4 * e]; ss[j] = edges[4 * e + 2]; }
            else      { rr[j] = edges[2 * e]; ss[j] = edges[2 * e + 1]; }
            rk[j] = atomicAdd(&h[rr[j] >> 8], 1);
        }
    }
    __syncthreads();
    for (int i = tid; i < NB; i += 1024) base[i] = h[i] ? atomicAdd(&bucketCursor[i], h[i]) : 0;
    __syncthreads();
    #pragma unroll
    for (int j = 0; j < 4; ++j) {
        if (rr[j] >= 0) {
            int b = rr[j] >> 8;
            tmp[base[b] + rk[j]] = (((unsigned)rr[j]) << 16) | (unsigned)ss[j];
        }
    }
}

__launch_bounds__(1024)
__global__ void fine_scatter_kernel(const unsigned int* __restrict__ tmp, const int* __restrict__ bucketStart,
                                    int* __restrict__ row_start, int* __restrict__ edge_send, int N, int E) {
    __shared__ int cnt[BN_NODES];
    __shared__ int cur[BN_NODES];
    __shared__ int vsave[BN_NODES];
    __shared__ int wtot[4];
    int b = blockIdx.x;
    int nodeBase = b * BN_NODES;
    int tid = threadIdx.x;
    if (tid < BN_NODES) cnt[tid] = 0;
    __syncthreads();
    int start = bucketStart[b], end = bucketStart[b + 1];
    for (int i = start + tid; i < end; i += 1024)
        atomicAdd(&cnt[(tmp[i] >> 16) - nodeBase], 1);
    __syncthreads();
    if (tid < BN_NODES) {
        int w = tid >> 6, l = tid & 63;
        int v = cnt[tid];
        vsave[tid] = v;
        int x = v;
        #pragma unroll
        for (int off = 1; off < 64; off <<= 1) {
            int y = __shfl_up(x, off, 64);
            if (l >= off) x += y;
        }
        cur[tid] = x;                 // inclusive (per 64-wide group)
        if (l == 63) wtot[w] = x;
    }
    __syncthreads();
    if (tid < BN_NODES) {
        int w = tid >> 6;
        int add = 0;
        for (int k = 0; k < w; ++k) add += wtot[k];
        int excl = cur[tid] - vsave[tid] + add;
        int node = nodeBase + tid;
        if (node < N) row_start[node] = start + excl;
        cur[tid] = start + excl;
    }
    if (tid == 0 && b == NB - 1) row_start[N] = E;
    __syncthreads();
    for (int i = start + tid; i < end; i += 1024) {
        unsigned p = tmp[i];
        int rl = (int)(p >> 16) - nodeBase;
        int pos = atomicAdd(&cur[rl], 1);
        edge_send[pos] = (int)(p & 0xFFFFu);
    }
}

// ---------------- Aggregation: one wave per node, lane = feature ----------------

__global__ void aggregate_kernel(const float* __restrict__ attr, const int* __restrict__ row_start,
                                 const int* __restrict__ edge_send,
                                 unsigned short* __restrict__ Xhi, unsigned short* __restrict__ Xlo,
                                 float* __restrict__ scaleArr, int N) {
    int gwid = (blockIdx.x * blockDim.x + threadIdx.x) >> 6;
    int lane = threadIdx.x & 63;
    if (gwid >= N) return;
    int beg = row_start[gwid], end = row_start[gwid + 1];
    float sum = 0.f, mx = -INFINITY;
    for (int base = beg; base < end; base += 64) {
        int cnt = end - base; if (cnt > 64) cnt = 64;
        int ii = base + lane; if (ii >= end) ii = end - 1;
        int il = edge_send[ii];                       // coalesced, one load per wave-chunk
        int j = 0;
        for (; j + 4 <= cnt; j += 4) {
            int s0 = __shfl(il, j + 0, 64);
            int s1 = __shfl(il, j + 1, 64);
            int s2 = __shfl(il, j + 2, 64);
            int s3 = __shfl(il, j + 3, 64);
            float v0 = attr[(size_t)s0 * F_DIM + lane];
            float v1 = attr[(size_t)s1 * F_DIM + lane];
            float v2 = attr[(size_t)s2 * F_DIM + lane];
            float v3 = attr[(size_t)s3 * F_DIM + lane];
            sum += v0 + v1 + v2 + v3;
            mx = fmaxf(mx, fmaxf(fmaxf(v0, v1), fmaxf(v2, v3)));
        }
        for (; j < cnt; ++j) {
            int s = __shfl(il, j, 64);
            float vv = attr[(size_t)s * F_DIM + lane];
            sum += vv;
            mx = fmaxf(mx, vv);
        }
    }
    int c = end - beg;
    float deg = fmaxf((float)c, 1.f);
    float mean = sum / deg;
    if (c == 0) mx = 0.f;
    size_t rb = (size_t)gwid * K_DIM;
    unsigned short h0 = f2bf(mean);
    Xhi[rb + lane] = h0;        Xlo[rb + lane] = f2bf(mean - bf2f(h0));
    unsigned short h1 = f2bf(mx);
    Xhi[rb + 64 + lane] = h1;   Xlo[rb + 64 + lane] = f2bf(mx - bf2f(h1));
    unsigned short h2 = f2bf(sum);
    Xhi[rb + 128 + lane] = h2;  Xlo[rb + 128 + lane] = f2bf(sum - bf2f(h2));
    if (lane == 0) scaleArr[gwid] = logf(deg + 1.f) * 0.43429448190325176f;
}

// ---------------- Weight fold + transpose + bf16 hi/lo split ----------------

__global__ void wprep_kernel(const float* __restrict__ W,
                             unsigned short* __restrict__ WtHi, unsigned short* __restrict__ WtLo) {
    int i = blockIdx.x * blockDim.x + threadIdx.x;
    if (i >= 256 * K_DIM) return;
    int n = i / K_DIM, k = i - n * K_DIM;
    int base = (k >> 6) * 192 + (k & 63);
    float v;
    if (n < 128) v = W[(size_t)base * U_DIM + n];
    else {
        int c = n - 128;
        v = W[(size_t)(base + 64) * U_DIM + c] + W[(size_t)(base + 128) * U_DIM + c];
    }
    unsigned short hi = f2bf(v);
    WtHi[i] = hi;
    WtLo[i] = f2bf(v - bf2f(hi));
}

// ---------------- MFMA GEMM: out = relu(X@Wa + scale*(X@Wb) + b), fused BN stats ----------------
// Block: 64 rows, 4 waves; wave = 16 rows x 256 cols. K-chunk = 32.
// T14 async-STAGE: next chunk's W (and A frags) prefetched into REGISTERS before
// the current chunk's MFMA loop; LDS write happens after the post-compute barrier,
// so global latency hides under the 48-MFMA compute phase.
// LDS: one 32 KB buffer, Bhi slots 0-3 / Blo slots 4-7 per n, XOR-swizzled (2-way max).

__launch_bounds__(256, 3)
__global__ void gemm_kernel(const unsigned short* __restrict__ Xhi, const unsigned short* __restrict__ Xlo,
                            const unsigned short* __restrict__ WtHi, const unsigned short* __restrict__ WtLo,
                            const float* __restrict__ scaleArr, const float* __restrict__ bias,
                            float* __restrict__ out, float* __restrict__ stats, int N) {
    __shared__ unsigned short Bs[2048 * 8];   // 2048 x 16B slots = 32 KB
    __shared__ float sstat[256];

    int tid = threadIdx.x;
    int wave = tid >> 6, lane = tid & 63;
    int q = lane >> 4, c16 = lane & 15;
    int rowBase = blockIdx.x * 64 + wave * 16;

    f32x4 acc[16];
    #pragma unroll
    for (int nt = 0; nt < 16; ++nt) acc[nt] = (f32x4)(0.f);
    sstat[tid] = 0.f;

    int r = rowBase + c16; if (r > N - 1) r = N - 1;
    const size_t rowOff = (size_t)r * K_DIM + q * 8;

    // prologue: stage chunk 0 into LDS, load A frags for chunk 0
    #pragma unroll
    for (int i = 0; i < 8; ++i) {
        int s = tid + i * 256;
        int n = s >> 3, j = s & 7;
        int dslot = (s & ~7) | (j ^ (n & 7));
        const unsigned short* src = (j < 4)
            ? &WtHi[(size_t)n * K_DIM + j * 8]
            : &WtLo[(size_t)n * K_DIM + (j - 4) * 8];
        ((us8*)Bs)[dslot] = *(const us8*)src;
    }
    bf16x8 ahc = *(const bf16x8*)&Xhi[rowOff];
    bf16x8 alc = *(const bf16x8*)&Xlo[rowOff];
    __syncthreads();

    #pragma unroll
    for (int kc = 0; kc < 6; ++kc) {
        // ---- T14: issue next-chunk loads into registers (latency hides under MFMAs) ----
        us8 pre[8];
        bf16x8 ahn, aln;
        if (kc < 5) {
            #pragma unroll
            for (int i = 0; i < 8; ++i) {
                int s = tid + i * 256;
                int n = s >> 3, j = s & 7;
                const unsigned short* src = (j < 4)
                    ? &WtHi[(size_t)n * K_DIM + (kc + 1) * 32 + j * 8]
                    : &WtLo[(size_t)n * K_DIM + (kc + 1) * 32 + (j - 4) * 8];
                pre[i] = *(const us8*)src;
            }
            ahn = *(const bf16x8*)&Xhi[rowOff + (kc + 1) * 32];
            aln = *(const bf16x8*)&Xlo[rowOff + (kc + 1) * 32];
        }
        // ---- compute current chunk ----
        #pragma unroll
        for (int nt = 0; nt < 16; ++nt) {
            int n = nt * 16 + c16;
            int sh = (n << 3) | (q ^ (n & 7));
            int sl = (n << 3) | ((q + 4) ^ (n & 7));
            bf16x8 bh = ((const bf16x8*)Bs)[sh];
            bf16x8 bl = ((const bf16x8*)Bs)[sl];
            acc[nt] = __builtin_amdgcn_mfma_f32_16x16x32_bf16(ahc, bh, acc[nt], 0, 0, 0);
            acc[nt] = __builtin_amdgcn_mfma_f32_16x16x32_bf16(ahc, bl, acc[nt], 0, 0, 0);
            acc[nt] = __builtin_amdgcn_mfma_f32_16x16x32_bf16(alc, bh, acc[nt], 0, 0, 0);
        }
        __syncthreads();                 // all waves done reading Bs
        if (kc < 5) {
            #pragma unroll
            for (int i = 0; i < 8; ++i) {
                int s = tid + i * 256;
                int n = s >> 3, j = s & 7;
                int dslot = (s & ~7) | (j ^ (n & 7));
                ((us8*)Bs)[dslot] = pre[i];
            }
            ahc = ahn; alc = aln;
        }
        __syncthreads();                 // next chunk visible
    }

    // ---- epilogue: combine Wa/Wb, bias, relu, store + fused BN partial stats ----
    int rg = rowBase + q * 4;
    float scv[4]; int vld[4];
    #pragma unroll
    for (int j = 0; j < 4; ++j) {
        int rr = rg + j;
        vld[j] = (rr < N);
        scv[j] = vld[j] ? scaleArr[rr] : 0.f;
    }
    #pragma unroll
    for (int nt = 0; nt < 8; ++nt) {
        int col = nt * 16 + c16;
        float bcol = bias[col];
        f32x4 va = acc[nt];
        f32x4 vb = acc[nt + 8];
        float s = 0.f, s2 = 0.f;
        #pragma unroll
        for (int j = 0; j < 4; ++j) {
            if (vld[j]) {
                float h = fmaxf(fmaf(scv[j], vb[j], va[j]) + bcol, 0.f);
                out[(size_t)(rg + j) * U_DIM + col] = h;
                s += h;
                s2 = fmaf(h, h, s2);
            }
        }
        s  += __shfl_xor(s, 16, 64);  s  += __shfl_xor(s, 32, 64);
        s2 += __shfl_xor(s2, 16, 64); s2 += __shfl_xor(s2, 32, 64);
        if (q == 0) {
            atomicAdd(&sstat[col], s);
            atomicAdd(&sstat[128 + col], s2);
        }
    }
    __syncthreads();
    atomicAdd(&stats[tid], sstat[tid]);   // stats[0..127]=sum, [128..255]=sumsq
}

// ---------------- BatchNorm finalize + apply ----------------

__global__ void finalize_kernel(const float* __restrict__ stats, float* __restrict__ ab,
                                const float* __restrict__ gamma, const float* __restrict__ beta, int N) {
    int c = threadIdx.x;   // 128 threads
    float inv = 1.f / (float)N;
    float mean = stats[c] * inv;
    float var = stats[128 + c] * inv - mean * mean;
    float rstd = rsqrtf(var + EPS_LN);
    float sc = gamma[c] * rstd;
    ab[c] = sc;
    ab[128 + c] = fmaf(-mean, sc, beta[c]);
}

__global__ void norm_kernel(float* __restrict__ h, const float* __restrict__ ab, int total4) {
    int i = blockIdx.x * blockDim.x + threadIdx.x;
    if (i >= total4) return;
    int c0 = (i * 4) & 127;
    float4 v = ((const float4*)h)[i];
    float4 o;
    o.x = fmaf(v.x, ab[c0 + 0], ab[128 + c0 + 0]);
    o.y = fmaf(v.y, ab[c0 + 1], ab[128 + c0 + 1]);
    o.z = fmaf(v.z, ab[c0 + 2], ab[128 + c0 + 2]);
    o.w = fmaf(v.w, ab[c0 + 3], ab[128 + c0 + 3]);
    ((float4*)h)[i] = o;
}

// ---------------- launch ----------------

extern "C" void kernel_launch(void* const* d_in, const int* in_sizes, int n_in,
                              void* d_out, int out_size, void* d_ws, size_t ws_size,
                              hipStream_t stream) {
    const float* attr        = (const float*)d_in[0];
    const int*   edges       = (const int*)d_in[1];   // int32 or int64 (probed)
    const float* W           = (const float*)d_in[2];
    const float* bias        = (const float*)d_in[3];
    const float* gamma       = (const float*)d_in[4];
    const float* beta        = (const float*)d_in[5];
    float* out = (float*)d_out;

    const int N = N_NODES, E = E_EDGES;

    char* ws = (char*)d_ws;
    size_t off = 0;
    auto alloc = [&](size_t bytes) -> void* {
        void* p = ws + off;
        off = (off + bytes + 255) & ~(size_t)255;
        return p;
    };
    int*   row_start    = (int*)alloc((size_t)(N + 1) * 4);
    int*   edge_send    = (int*)alloc((size_t)E * 4);
    unsigned int* tmp   = (unsigned int*)alloc((size_t)E * 4);
    float* scaleArr     = (float*)alloc((size_t)N * 4);
    float* stats        = (float*)alloc(512 * 4);
    int*   flag         = (int*)alloc(256);
    int*   bhist        = (int*)alloc(NB * 4);
    int*   bucketStart  = (int*)alloc((NB + 1) * 4);
    int*   bucketCursor = (int*)alloc(NB * 4);
    unsigned short* WtHi = (unsigned short*)alloc((size_t)256 * K_DIM * 2);
    unsigned short* WtLo = (unsigned short*)alloc((size_t)256 * K_DIM * 2);
    unsigned short* Xhi  = (unsigned short*)alloc((size_t)N * K_DIM * 2);
    unsigned short* Xlo  = (unsigned short*)alloc((size_t)N * K_DIM * 2);
    float* ab = stats + 256;

    hipMemsetAsync(bhist, 0, NB * 4, stream);
    hipMemsetAsync(stats, 0, 512 * 4, stream);

    const int EB = (E + 4095) / 4096;   // 196 edge blocks (1024 thr x 4 edges)

    probe_kernel<<<1, 256, 0, stream>>>(edges, flag);
    bucket_hist_kernel<<<EB, 1024, 0, stream>>>(edges, flag, bhist, E);
    bucket_scan_kernel<<<1, 256, 0, stream>>>(bhist, bucketStart, bucketCursor, E);
    bucket_scatter_kernel<<<EB, 1024, 0, stream>>>(edges, flag, bucketCursor, tmp, E);
    fine_scatter_kernel<<<NB, 1024, 0, stream>>>(tmp, bucketStart, row_start, edge_send, N, E);
    aggregate_kernel<<<(N + 3) / 4, 256, 0, stream>>>(attr, row_start, edge_send, Xhi, Xlo, scaleArr, N);
    wprep_kernel<<<(256 * K_DIM + 255) / 256, 256, 0, stream>>>(W, WtHi, WtLo);
    gemm_kernel<<<(N + 63) / 64, 256, 0, stream>>>(Xhi, Xlo, WtHi, WtLo, scaleArr, bias, out, stats, N);
    finalize_kernel<<<1, 128, 0, stream>>>(stats, ab, gamma, beta, N);
    norm_kernel<<<(N * U_DIM / 4 + 255) / 256, 256, 0, stream>>>(out, ab, N * U_DIM / 4);
}

// Round 15
// 204.590 us; speedup vs baseline: 1.1068x; 1.1068x over previous
//
#include <hip/hip_runtime.h>
#include <math.h>

#define N_NODES 50000
#define F_DIM 64
#define E_EDGES 800000
#define U_DIM 128
#define K_DIM 192
#define EPS_LN 0.001f
#define NB 196           // ceil(N/256) node buckets
#define BN_NODES 256     // nodes per bucket

typedef __attribute__((ext_vector_type(8))) short bf16x8;
typedef __attribute__((ext_vector_type(4))) float f32x4;
typedef __attribute__((ext_vector_type(8))) unsigned short us8;

__device__ __forceinline__ unsigned short f2bf(float x) {
    unsigned u = __builtin_bit_cast(unsigned, x);
    unsigned r = (u + 0x7FFFu + ((u >> 16) & 1u)) >> 16;   // RNE
    return (unsigned short)r;
}
__device__ __forceinline__ float bf2f(unsigned short h) {
    unsigned u = ((unsigned)h) << 16;
    return __builtin_bit_cast(float, u);
}

// ---------------- dtype probe ----------------
__global__ void probe_kernel(const int* __restrict__ e, int* __restrict__ flag) {
    __shared__ int nz;
    if (threadIdx.x == 0) nz = 0;
    __syncthreads();
    int i = threadIdx.x;
    if (e[4 * i + 1] != 0 || e[4 * i + 3] != 0) atomicAdd(&nz, 1);
    __syncthreads();
    if (threadIdx.x == 0) flag[0] = (nz == 0) ? 1 : 0;   // 1 = int64 layout
}

// ---------------- CSR build: 2-level bucket sort, LDS-atomic based ----------------

__global__ void bucket_hist_kernel(const int* __restrict__ edges, const int* __restrict__ flag,
                                   int* __restrict__ bhist, int E) {
    __shared__ int h[NB];
    int tid = threadIdx.x;
    for (int i = tid; i < NB; i += 1024) h[i] = 0;
    __syncthreads();
    int is64 = flag[0];
    int e0 = blockIdx.x * 4096 + tid * 4;
    #pragma unroll
    for (int j = 0; j < 4; ++j) {
        int e = e0 + j;
        if (e < E) {
            int r = is64 ? edges[4 * e] : edges[2 * e];
            atomicAdd(&h[r >> 8], 1);
        }
    }
    __syncthreads();
    for (int i = tid; i < NB; i += 1024) if (h[i]) atomicAdd(&bhist[i], h[i]);
}

__global__ void bucket_scan_kernel(const int* __restrict__ bhist, int* __restrict__ bucketStart,
                                   int* __restrict__ bucketCursor, int E) {
    __shared__ int wtot[4];
    int tid = threadIdx.x;             // 256
    int w = tid >> 6, l = tid & 63;
    int v = (tid < NB) ? bhist[tid] : 0;
    int x = v;
    #pragma unroll
    for (int off = 1; off < 64; off <<= 1) {
        int y = __shfl_up(x, off, 64);
        if (l >= off) x += y;
    }
    if (l == 63) wtot[w] = x;
    __syncthreads();
    int add = 0;
    for (int k = 0; k < w; ++k) add += wtot[k];
    int excl = x - v + add;
    if (tid < NB) { bucketStart[tid] = excl; bucketCursor[tid] = excl; }
    if (tid == 0) bucketStart[NB] = E;
}

__global__ void bucket_scatter_kernel(const int* __restrict__ edges, const int* __restrict__ flag,
                                      int* __restrict__ bucketCursor, unsigned int* __restrict__ tmp, int E) {
    __shared__ int h[NB];
    __shared__ int base[NB];
    int tid = threadIdx.x;
    for (int i = tid; i < NB; i += 1024) h[i] = 0;
    __syncthreads();
    int is64 = flag[0];
    int e0 = blockIdx.x * 4096 + tid * 4;
    int rr[4], ss[4], rk[4];
    #pragma unroll
    for (int j = 0; j < 4; ++j) {
        int e = e0 + j;
        rr[j] = -1; ss[j] = 0; rk[j] = 0;
        if (e < E) {
            if (is64) { rr[j] = edges[4 * e]; ss[j] = edges[4 * e + 2]; }
            else      { rr[j] = edges[2 * e]; ss[j] = edges[2 * e + 1]; }
            rk[j] = atomicAdd(&h[rr[j] >> 8], 1);
        }
    }
    __syncthreads();
    for (int i = tid; i < NB; i += 1024) base[i] = h[i] ? atomicAdd(&bucketCursor[i], h[i]) : 0;
    __syncthreads();
    #pragma unroll
    for (int j = 0; j < 4; ++j) {
        if (rr[j] >= 0) {
            int b = rr[j] >> 8;
            tmp[base[b] + rk[j]] = (((unsigned)rr[j]) << 16) | (unsigned)ss[j];
        }
    }
}

__launch_bounds__(1024)
__global__ void fine_scatter_kernel(const unsigned int* __restrict__ tmp, const int* __restrict__ bucketStart,
                                    int* __restrict__ row_start, int* __restrict__ edge_send, int N, int E) {
    __shared__ int cnt[BN_NODES];
    __shared__ int cur[BN_NODES];
    __shared__ int vsave[BN_NODES];
    __shared__ int wtot[4];
    int b = blockIdx.x;
    int nodeBase = b * BN_NODES;
    int tid = threadIdx.x;
    if (tid < BN_NODES) cnt[tid] = 0;
    __syncthreads();
    int start = bucketStart[b], end = bucketStart[b + 1];
    for (int i = start + tid; i < end; i += 1024)
        atomicAdd(&cnt[(tmp[i] >> 16) - nodeBase], 1);
    __syncthreads();
    if (tid < BN_NODES) {
        int w = tid >> 6, l = tid & 63;
        int v = cnt[tid];
        vsave[tid] = v;
        int x = v;
        #pragma unroll
        for (int off = 1; off < 64; off <<= 1) {
            int y = __shfl_up(x, off, 64);
            if (l >= off) x += y;
        }
        cur[tid] = x;                 // inclusive (per 64-wide group)
        if (l == 63) wtot[w] = x;
    }
    __syncthreads();
    if (tid < BN_NODES) {
        int w = tid >> 6;
        int add = 0;
        for (int k = 0; k < w; ++k) add += wtot[k];
        int excl = cur[tid] - vsave[tid] + add;
        int node = nodeBase + tid;
        if (node < N) row_start[node] = start + excl;
        cur[tid] = start + excl;
    }
    if (tid == 0 && b == NB - 1) row_start[N] = E;
    __syncthreads();
    for (int i = start + tid; i < end; i += 1024) {
        unsigned p = tmp[i];
        int rl = (int)(p >> 16) - nodeBase;
        int pos = atomicAdd(&cur[rl], 1);
        edge_send[pos] = (int)(p & 0xFFFFu);
    }
}

// ---------------- Aggregation: one wave per node, lane = feature ----------------

__global__ void aggregate_kernel(const float* __restrict__ attr, const int* __restrict__ row_start,
                                 const int* __restrict__ edge_send,
                                 unsigned short* __restrict__ Xhi, unsigned short* __restrict__ Xlo,
                                 float* __restrict__ scaleArr, int N) {
    int gwid = (blockIdx.x * blockDim.x + threadIdx.x) >> 6;
    int lane = threadIdx.x & 63;
    if (gwid >= N) return;
    int beg = row_start[gwid], end = row_start[gwid + 1];
    float sum = 0.f, mx = -INFINITY;
    for (int base = beg; base < end; base += 64) {
        int cnt = end - base; if (cnt > 64) cnt = 64;
        int ii = base + lane; if (ii >= end) ii = end - 1;
        int il = edge_send[ii];                       // coalesced, one load per wave-chunk
        int j = 0;
        for (; j + 4 <= cnt; j += 4) {
            int s0 = __shfl(il, j + 0, 64);
            int s1 = __shfl(il, j + 1, 64);
            int s2 = __shfl(il, j + 2, 64);
            int s3 = __shfl(il, j + 3, 64);
            float v0 = attr[(size_t)s0 * F_DIM + lane];
            float v1 = attr[(size_t)s1 * F_DIM + lane];
            float v2 = attr[(size_t)s2 * F_DIM + lane];
            float v3 = attr[(size_t)s3 * F_DIM + lane];
            sum += v0 + v1 + v2 + v3;
            mx = fmaxf(mx, fmaxf(fmaxf(v0, v1), fmaxf(v2, v3)));
        }
        for (; j < cnt; ++j) {
            int s = __shfl(il, j, 64);
            float vv = attr[(size_t)s * F_DIM + lane];
            sum += vv;
            mx = fmaxf(mx, vv);
        }
    }
    int c = end - beg;
    float deg = fmaxf((float)c, 1.f);
    float mean = sum / deg;
    if (c == 0) mx = 0.f;
    size_t rb = (size_t)gwid * K_DIM;
    unsigned short h0 = f2bf(mean);
    Xhi[rb + lane] = h0;        Xlo[rb + lane] = f2bf(mean - bf2f(h0));
    unsigned short h1 = f2bf(mx);
    Xhi[rb + 64 + lane] = h1;   Xlo[rb + 64 + lane] = f2bf(mx - bf2f(h1));
    unsigned short h2 = f2bf(sum);
    Xhi[rb + 128 + lane] = h2;  Xlo[rb + 128 + lane] = f2bf(sum - bf2f(h2));
    if (lane == 0) scaleArr[gwid] = logf(deg + 1.f) * 0.43429448190325176f;
}

// ---------------- Weight fold + transpose + bf16 hi/lo split ----------------

__global__ void wprep_kernel(const float* __restrict__ W,
                             unsigned short* __restrict__ WtHi, unsigned short* __restrict__ WtLo) {
    int i = blockIdx.x * blockDim.x + threadIdx.x;
    if (i >= 256 * K_DIM) return;
    int n = i / K_DIM, k = i - n * K_DIM;
    int base = (k >> 6) * 192 + (k & 63);
    float v;
    if (n < 128) v = W[(size_t)base * U_DIM + n];
    else {
        int c = n - 128;
        v = W[(size_t)(base + 64) * U_DIM + c] + W[(size_t)(base + 128) * U_DIM + c];
    }
    unsigned short hi = f2bf(v);
    WtHi[i] = hi;
    WtLo[i] = f2bf(v - bf2f(hi));
}

// ---------------- MFMA GEMM: out = relu(X@Wa + scale*(X@Wb) + b), fused BN stats ----------------
// Block: 64 rows, 4 waves; wave = 16 rows x 256 cols. K-chunk = 32.
// Staging via global_load_lds (16B, direct-to-LDS DMA, no VGPR round trip).
// gload_lds writes LINEAR LDS (wave base + lane*16), so the XOR swizzle is applied
// to the GLOBAL SOURCE address (involution: j_src = (t&7) ^ ((t>>3)&7)); read-side
// swizzled formulas unchanged (rule 21: same involution on both sides).
// A fragments for all 6 chunks hoisted to registers up front (static unroll).

__launch_bounds__(256, 3)
__global__ void gemm_kernel(const unsigned short* __restrict__ Xhi, const unsigned short* __restrict__ Xlo,
                            const unsigned short* __restrict__ WtHi, const unsigned short* __restrict__ WtLo,
                            const float* __restrict__ scaleArr, const float* __restrict__ bias,
                            float* __restrict__ out, float* __restrict__ stats, int N) {
    __shared__ unsigned short Bs[2048 * 8];   // 2048 x 16B slots = 32 KB
    __shared__ float sstat[256];

    int tid = threadIdx.x;
    int wave = tid >> 6, lane = tid & 63;
    int q = lane >> 4, c16 = lane & 15;
    int rowBase = blockIdx.x * 64 + wave * 16;

    f32x4 acc[16];
    #pragma unroll
    for (int nt = 0; nt < 16; ++nt) acc[nt] = (f32x4)(0.f);
    sstat[tid] = 0.f;

    int r = rowBase + c16; if (r > N - 1) r = N - 1;
    const size_t rowOff = (size_t)r * K_DIM + q * 8;

    // ---- hoist ALL A fragments (6 chunks x hi/lo, 48 VGPRs, static indices) ----
    bf16x8 ah[6], al[6];
    #pragma unroll
    for (int kc = 0; kc < 6; ++kc) {
        ah[kc] = *(const bf16x8*)&Xhi[rowOff + kc * 32];
        al[kc] = *(const bf16x8*)&Xlo[rowOff + kc * 32];
    }

    // per-wave staging: 8 x global_load_lds(16B), linear LDS dest, pre-swizzled src
    auto stage = [&](int kc) {
        #pragma unroll
        for (int i = 0; i < 8; ++i) {
            int t = (wave * 8 + i) * 64 + lane;     // linear 16B-slot id
            int n = t >> 3;
            int j = (t & 7) ^ (n & 7);              // involution: source j for this slot
            const unsigned short* src = (j < 4)
                ? &WtHi[(size_t)n * K_DIM + kc * 32 + j * 8]
                : &WtLo[(size_t)n * K_DIM + kc * 32 + (j - 4) * 8];
            __builtin_amdgcn_global_load_lds(
                (const __attribute__((address_space(1))) void*)src,
                (__attribute__((address_space(3))) void*)((char*)Bs + (size_t)(wave * 8 + i) * 1024),
                16, 0, 0);
        }
    };

    stage(0);
    __syncthreads();

    #pragma unroll
    for (int kc = 0; kc < 6; ++kc) {
        #pragma unroll
        for (int nt = 0; nt < 16; ++nt) {
            int n = nt * 16 + c16;
            int sh = (n << 3) | (q ^ (n & 7));
            int sl = (n << 3) | ((q + 4) ^ (n & 7));
            bf16x8 bh = ((const bf16x8*)Bs)[sh];
            bf16x8 bl = ((const bf16x8*)Bs)[sl];
            acc[nt] = __builtin_amdgcn_mfma_f32_16x16x32_bf16(ah[kc], bh, acc[nt], 0, 0, 0);
            acc[nt] = __builtin_amdgcn_mfma_f32_16x16x32_bf16(ah[kc], bl, acc[nt], 0, 0, 0);
            acc[nt] = __builtin_amdgcn_mfma_f32_16x16x32_bf16(al[kc], bh, acc[nt], 0, 0, 0);
        }
        __syncthreads();                 // all waves done reading Bs
        if (kc < 5) {
            stage(kc + 1);
            __syncthreads();             // staged data visible
        }
    }

    // ---- epilogue: combine Wa/Wb, bias, relu, store + fused BN partial stats ----
    int rg = rowBase + q * 4;
    float scv[4]; int vld[4];
    #pragma unroll
    for (int j = 0; j < 4; ++j) {
        int rr = rg + j;
        vld[j] = (rr < N);
        scv[j] = vld[j] ? scaleArr[rr] : 0.f;
    }
    #pragma unroll
    for (int nt = 0; nt < 8; ++nt) {
        int col = nt * 16 + c16;
        float bcol = bias[col];
        f32x4 va = acc[nt];
        f32x4 vb = acc[nt + 8];
        float s = 0.f, s2 = 0.f;
        #pragma unroll
        for (int j = 0; j < 4; ++j) {
            if (vld[j]) {
                float h = fmaxf(fmaf(scv[j], vb[j], va[j]) + bcol, 0.f);
                out[(size_t)(rg + j) * U_DIM + col] = h;
                s += h;
                s2 = fmaf(h, h, s2);
            }
        }
        s  += __shfl_xor(s, 16, 64);  s  += __shfl_xor(s, 32, 64);
        s2 += __shfl_xor(s2, 16, 64); s2 += __shfl_xor(s2, 32, 64);
        if (q == 0) {
            atomicAdd(&sstat[col], s);
            atomicAdd(&sstat[128 + col], s2);
        }
    }
    __syncthreads();
    atomicAdd(&stats[tid], sstat[tid]);   // stats[0..127]=sum, [128..255]=sumsq
}

// ---------------- BatchNorm finalize + apply ----------------

__global__ void finalize_kernel(const float* __restrict__ stats, float* __restrict__ ab,
                                const float* __restrict__ gamma, const float* __restrict__ beta, int N) {
    int c = threadIdx.x;   // 128 threads
    float inv = 1.f / (float)N;
    float mean = stats[c] * inv;
    float var = stats[128 + c] * inv - mean * mean;
    float rstd = rsqrtf(var + EPS_LN);
    float sc = gamma[c] * rstd;
    ab[c] = sc;
    ab[128 + c] = fmaf(-mean, sc, beta[c]);
}

__global__ void norm_kernel(float* __restrict__ h, const float* __restrict__ ab, int total4) {
    int i = blockIdx.x * blockDim.x + threadIdx.x;
    if (i >= total4) return;
    int c0 = (i * 4) & 127;
    float4 v = ((const float4*)h)[i];
    float4 o;
    o.x = fmaf(v.x, ab[c0 + 0], ab[128 + c0 + 0]);
    o.y = fmaf(v.y, ab[c0 + 1], ab[128 + c0 + 1]);
    o.z = fmaf(v.z, ab[c0 + 2], ab[128 + c0 + 2]);
    o.w = fmaf(v.w, ab[c0 + 3], ab[128 + c0 + 3]);
    ((float4*)h)[i] = o;
}

// ---------------- launch ----------------

extern "C" void kernel_launch(void* const* d_in, const int* in_sizes, int n_in,
                              void* d_out, int out_size, void* d_ws, size_t ws_size,
                              hipStream_t stream) {
    const float* attr        = (const float*)d_in[0];
    const int*   edges       = (const int*)d_in[1];   // int32 or int64 (probed)
    const float* W           = (const float*)d_in[2];
    const float* bias        = (const float*)d_in[3];
    const float* gamma       = (const float*)d_in[4];
    const float* beta        = (const float*)d_in[5];
    float* out = (float*)d_out;

    const int N = N_NODES, E = E_EDGES;

    char* ws = (char*)d_ws;
    size_t off = 0;
    auto alloc = [&](size_t bytes) -> void* {
        void* p = ws + off;
        off = (off + bytes + 255) & ~(size_t)255;
        return p;
    };
    int*   row_start    = (int*)alloc((size_t)(N + 1) * 4);
    int*   edge_send    = (int*)alloc((size_t)E * 4);
    unsigned int* tmp   = (unsigned int*)alloc((size_t)E * 4);
    float* scaleArr     = (float*)alloc((size_t)N * 4);
    float* stats        = (float*)alloc(512 * 4);
    int*   flag         = (int*)alloc(256);
    int*   bhist        = (int*)alloc(NB * 4);
    int*   bucketStart  = (int*)alloc((NB + 1) * 4);
    int*   bucketCursor = (int*)alloc(NB * 4);
    unsigned short* WtHi = (unsigned short*)alloc((size_t)256 * K_DIM * 2);
    unsigned short* WtLo = (unsigned short*)alloc((size_t)256 * K_DIM * 2);
    unsigned short* Xhi  = (unsigned short*)alloc((size_t)N * K_DIM * 2);
    unsigned short* Xlo  = (unsigned short*)alloc((size_t)N * K_DIM * 2);
    float* ab = stats + 256;

    hipMemsetAsync(bhist, 0, NB * 4, stream);
    hipMemsetAsync(stats, 0, 512 * 4, stream);

    const int EB = (E + 4095) / 4096;   // 196 edge blocks (1024 thr x 4 edges)

    probe_kernel<<<1, 256, 0, stream>>>(edges, flag);
    bucket_hist_kernel<<<EB, 1024, 0, stream>>>(edges, flag, bhist, E);
    bucket_scan_kernel<<<1, 256, 0, stream>>>(bhist, bucketStart, bucketCursor, E);
    bucket_scatter_kernel<<<EB, 1024, 0, stream>>>(edges, flag, bucketCursor, tmp, E);
    fine_scatter_kernel<<<NB, 1024, 0, stream>>>(tmp, bucketStart, row_start, edge_send, N, E);
    aggregate_kernel<<<(N + 3) / 4, 256, 0, stream>>>(attr, row_start, edge_send, Xhi, Xlo, scaleArr, N);
    wprep_kernel<<<(256 * K_DIM + 255) / 256, 256, 0, stream>>>(W, WtHi, WtLo);
    gemm_kernel<<<(N + 63) / 64, 256, 0, stream>>>(Xhi, Xlo, WtHi, WtLo, scaleArr, bias, out, stats, N);
    finalize_kernel<<<1, 128, 0, stream>>>(stats, ab, gamma, beta, N);
    norm_kernel<<<(N * U_DIM / 4 + 255) / 256, 256, 0, stream>>>(out, ab, N * U_DIM / 4);
}